// Round 1
// 302.673 us; speedup vs baseline: 1.1482x; 1.1482x over previous
//
#include <hip/hip_runtime.h>
#include <hip/hip_bf16.h>
#include <math.h>

#define S_LEN   2048
#define HIDDEN  2048
#define NHEADS  16
#define NKVH    4
#define HDIM    128

typedef short  short8  __attribute__((ext_vector_type(8)));
typedef float  floatx4 __attribute__((ext_vector_type(4)));
typedef __hip_bfloat16 bf16;

__device__ inline void async_copy16(const void* g, void* l) {
  __builtin_amdgcn_global_load_lds((__attribute__((address_space(1))) void*)(g),
                                   (__attribute__((address_space(3))) void*)(l),
                                   16, 0, 0);
}

__device__ inline unsigned short cvt1(float x) {
  bf16 t = __float2bfloat16(x);
  return *reinterpret_cast<unsigned short*>(&t);
}
__device__ inline float us2f(unsigned short u) {
  unsigned int v = ((unsigned int)u) << 16;
  return *reinterpret_cast<float*>(&v);
}

// fp32 -> bf16 for all three inputs in one launch; dst regions contiguous.
#define N8_H  1048576
#define N8_WQ  786432
#define N8_WO  524288
__global__ __launch_bounds__(256) void cvt_all(const float* __restrict__ h,
                                               const float* __restrict__ wq,
                                               const float* __restrict__ wo,
                                               unsigned short* __restrict__ dst) {
  const int i = blockIdx.x * 256 + threadIdx.x;
  if (i >= N8_H + N8_WQ + N8_WO) return;
  const float* src; int j;
  if (i < N8_H)              { src = h;  j = i; }
  else if (i < N8_H + N8_WQ) { src = wq; j = i - N8_H; }
  else                       { src = wo; j = i - N8_H - N8_WQ; }
  const float4 a = reinterpret_cast<const float4*>(src)[j * 2];
  const float4 b = reinterpret_cast<const float4*>(src)[j * 2 + 1];
  unsigned short o[8] = {cvt1(a.x), cvt1(a.y), cvt1(a.z), cvt1(a.w),
                         cvt1(b.x), cvt1(b.y), cvt1(b.z), cvt1(b.w)};
  *reinterpret_cast<short8*>(dst + (size_t)i * 8) = *reinterpret_cast<short8*>(o);
}

// ============================================================================
// 8-wave pipelined GEMM: C[M,N] = A[M,K] * B[N,K]^T, bf16 in, fp32 acc.
// Ring of 4 K-step slots (K-step = 32) in LDS; phase s computes slot s&3 and
// stages step s+3 into slot (s+3)&3. Counted vmcnt (never 0 in loop) + raw
// s_barrier keeps 3 K-steps of global_load_lds in flight across barriers.
// LDS layout per slot: A[BM][32] then B[256][32] bf16, 64B rows, with 16B-slot
// XOR swizzle  phys_slot = log_slot ^ ((row>>1)&3)  (2-way max on ds_read_b128;
// 2-way is free).  global_load_lds writes linearly, so the *global* source is
// pre-swizzled with the same involution (rule 21: both-sides-or-neither).
// MODE 0: BM=256, grid 12x16, fused RoPE epilogue -> qbuf/kbuf/vtbuf.
// MODE 1: BM=128, grid 8x32 (=256 blocks, 1/CU), Cout fp32 row-major.
// ============================================================================
template<int MODE>
__global__ __launch_bounds__(512, 2) void gemm8(const bf16* __restrict__ A,
                                                const bf16* __restrict__ B,
                                                bf16* __restrict__ qbuf,
                                                bf16* __restrict__ kbuf,
                                                bf16* __restrict__ vtbuf,
                                                float* __restrict__ Cout)
{
  constexpr int K      = 2048;
  constexpr int BM     = (MODE == 0) ? 256 : 128;
  constexpr int BN     = 256;
  constexpr int MF     = BM / 32;        // m-frags per wave (8 / 4)
  constexpr int AI     = BM / 128;       // A stage instrs per wave (2 / 1)
  constexpr int ABYTES = BM * 64;        // A region bytes per slot
  constexpr int SLOT   = (BM + BN) * 64; // slot bytes (32KB / 24KB)
  constexpr int NSTEP  = K / 32;         // 64

  __shared__ __align__(16) unsigned short smem[SLOT * 4 / 2];
  char* smb = (char*)smem;

  const int bn = blockIdx.x, bm = blockIdx.y;
  const int t = threadIdx.x, w = t >> 6, lane = t & 63;
  const int m16 = lane & 15, quad = lane >> 4;
  const int wmr = (w >> 2) * (BM / 2);   // wave row base within tile
  const int wn  = w & 3;

  // n-frag column map. MODE 0: each wave's frags pair (d, d+64) for RoPE
  // (ni^2 flips the +64 bit, like the old kernel's bcol scheme).
  int bcol[4];
#pragma unroll
  for (int ni = 0; ni < 4; ++ni)
    bcol[ni] = (MODE == 0)
             ? ((wn >> 1) * 128 + (wn & 1) * 32 + (ni & 1) * 16 + (ni >> 1) * 64)
             : (wn * 64 + ni * 16);

  // ds_read fragment byte offsets (swizzled), constant across steps
  int afo[MF], bfo[4];
#pragma unroll
  for (int mf = 0; mf < MF; ++mf) {
    const int r = wmr + mf * 16 + m16;
    afo[mf] = r * 64 + ((quad ^ ((r >> 1) & 3)) << 4);
  }
#pragma unroll
  for (int ni = 0; ni < 4; ++ni) {
    const int r = bcol[ni] + m16;
    bfo[ni] = ABYTES + r * 64 + ((quad ^ ((r >> 1) & 3)) << 4);
  }

  // staging: per-lane pre-swizzled global sources, linear wave-uniform LDS dest
  const bf16* srcA[AI]; int dstA[AI];
#pragma unroll
  for (int j = 0; j < AI; ++j) {
    const int ci  = w * AI + j;            // 1KB chunk id
    const int row = ci * 16 + (lane >> 2);
    const int sl  = (lane & 3) ^ ((row >> 1) & 3);
    srcA[j] = A + (size_t)(bm * BM + row) * K + sl * 8;
    dstA[j] = ci * 1024;
  }
  const bf16* srcB[2]; int dstB[2];
#pragma unroll
  for (int j = 0; j < 2; ++j) {
    const int ci  = w * 2 + j;
    const int row = ci * 16 + (lane >> 2);
    const int sl  = (lane & 3) ^ ((row >> 1) & 3);
    srcB[j] = B + (size_t)(bn * BN + row) * K + sl * 8;
    dstB[j] = ABYTES + ci * 1024;
  }

  auto stage = [&](int step, int slotbyte) {
#pragma unroll
    for (int j = 0; j < AI; ++j)
      async_copy16(srcA[j] + step * 32, smb + slotbyte + dstA[j]);
#pragma unroll
    for (int j = 0; j < 2; ++j)
      async_copy16(srcB[j] + step * 32, smb + slotbyte + dstB[j]);
  };

  const floatx4 zf = {0.f, 0.f, 0.f, 0.f};
  floatx4 acc[MF][4];
#pragma unroll
  for (int mf = 0; mf < MF; ++mf)
#pragma unroll
    for (int ni = 0; ni < 4; ++ni) acc[mf][ni] = zf;

  // prologue: 3 K-steps in flight
  stage(0, 0); stage(1, SLOT); stage(2, 2 * SLOT);

#pragma unroll 4
  for (int s = 0; s < NSTEP; ++s) {
    __builtin_amdgcn_sched_barrier(0);           // end-of-phase fence
    if constexpr (MODE == 0) asm volatile("s_waitcnt vmcnt(8)" ::: "memory");
    else                     asm volatile("s_waitcnt vmcnt(6)" ::: "memory");
    __builtin_amdgcn_s_barrier();
    __builtin_amdgcn_sched_barrier(0);           // nothing crosses the barrier
    const int sb = (s & 3) * SLOT;
    short8 af[MF], bfr[4];
#pragma unroll
    for (int mf = 0; mf < MF; ++mf)
      af[mf] = *reinterpret_cast<const short8*>(smb + sb + afo[mf]);
#pragma unroll
    for (int ni = 0; ni < 4; ++ni)
      bfr[ni] = *reinterpret_cast<const short8*>(smb + sb + bfo[ni]);
    // stage step s+3 into slot (s+3)&3 (== slot s-1, consumed last phase;
    // safe: all waves' reads of it completed before this phase's barrier).
    // Tail phases wrap and re-stage steps 0..2 with identical data: harmless.
    stage((s + 3) & (NSTEP - 1), ((s + 3) & 3) * SLOT);
    __builtin_amdgcn_s_setprio(1);
#pragma unroll
    for (int mf = 0; mf < MF; ++mf)
#pragma unroll
      for (int ni = 0; ni < 4; ++ni)
        acc[mf][ni] = __builtin_amdgcn_mfma_f32_16x16x32_bf16(af[mf], bfr[ni], acc[mf][ni], 0, 0, 0);
    __builtin_amdgcn_s_setprio(0);
  }
  __builtin_amdgcn_s_waitcnt(0);   // drain wrapped tail stages before exit

  if constexpr (MODE == 1) {
#pragma unroll
    for (int mf = 0; mf < MF; ++mf)
#pragma unroll
      for (int ni = 0; ni < 4; ++ni) {
        const int row0 = bm * BM + wmr + mf * 16 + quad * 4;
        const int col  = bn * BN + bcol[ni] + m16;
#pragma unroll
        for (int r = 0; r < 4; ++r)
          Cout[(size_t)(row0 + r) * HIDDEN + col] = acc[mf][ni][r];
      }
  } else {
    // ---- fused in-wave RoPE epilogue (same math as prior kernel) ----
    const int colbase = bn * BN;
    if (colbase < HIDDEN + NKVH * HDIM) {
      const bool isQ = (colbase < HIDDEN);
      const float post = isQ ? 0.08838834764831845f : 1.0f;
      float invf[2];
#pragma unroll
      for (int p = 0; p < 2; ++p)
        invf[p] = exp2f((float)((wn & 1) * 32 + p * 16 + m16) * -0.2076205059f);
#pragma unroll
      for (int mf = 0; mf < MF; ++mf) {
        const int row0 = bm * BM + wmr + mf * 16 + quad * 4;
#pragma unroll
        for (int r = 0; r < 4; ++r) {
          const int m = row0 + r;
          const int b = m >> 11, s = m & 2047;
          float sn[2], cs[2];
          __sincosf((float)s * invf[0], &sn[0], &cs[0]);
          __sincosf((float)s * invf[1], &sn[1], &cs[1]);
#pragma unroll
          for (int ni = 0; ni < 4; ++ni) {
            const int p = ni & 1;
            const float v  = acc[mf][ni][r];
            const float v2 = acc[mf][ni ^ 2][r];
            const float rot = ((ni < 2) ? (v * cs[p] - v2 * sn[p])
                                        : (v * cs[p] + v2 * sn[p])) * post;
            const int col = colbase + bcol[ni] + m16;
            if (isQ) {
              const int hh = col >> 7, d = col & 127;
              qbuf[(((size_t)(b * NHEADS + hh)) * S_LEN + s) * HDIM + d] = __float2bfloat16(rot);
            } else {
              const int nn = col - HIDDEN; const int hh = nn >> 7, d = nn & 127;
              kbuf[(((size_t)(b * NKVH + hh)) * S_LEN + s) * HDIM + d] = __float2bfloat16(rot);
            }
          }
        }
      }
    } else {
#pragma unroll
      for (int mf = 0; mf < MF; ++mf)
#pragma unroll
        for (int ni = 0; ni < 4; ++ni) {
          const int col = colbase + bcol[ni] + m16;
          const int nn = col - HIDDEN - NKVH * HDIM;
          const int hh = nn >> 7, d = nn & 127;
          const int row0 = bm * BM + wmr + mf * 16 + quad * 4;
#pragma unroll
          for (int r = 0; r < 4; ++r) {
            const int m = row0 + r;
            const int b = m >> 11, s = m & 2047;
            vtbuf[(((size_t)(b * NKVH + hh)) * HDIM + d) * S_LEN + s] =
                __float2bfloat16(acc[mf][ni][r]);
          }
        }
    }
  }
}

// ---------------- Attention phase A: split-K partials, max-free softmax ------
// Balanced chunks (<=27 iters), descending dispatch. nch==1 tiles are final:
// divide by row-sum and write abuf directly (skip partial round-trip).
__global__ __launch_bounds__(256) void attn_partial(const bf16* __restrict__ qbuf,
                                                    const bf16* __restrict__ kbuf,
                                                    const bf16* __restrict__ vtbuf,
                                                    unsigned short* __restrict__ pnum,
                                                    float* __restrict__ plsum,
                                                    bf16* __restrict__ abuf)
{
  __shared__ unsigned short Ks[2][4096];
  __shared__ unsigned short Vs[2][4096];
  __shared__ unsigned short Ps[4][1280];
  const int sidx = 110 - blockIdx.x;       // descending dispatch
  int i2, c, nch;
  if (sidx < 27)      { i2 = sidx;                     c = 0;              nch = 1; }
  else if (sidx < 81) { i2 = 27 + ((sidx - 27) >> 1);  c = (sidx - 27) & 1; nch = 2; }
  else                { i2 = 54 + (sidx - 81) / 3;     c = (sidx - 81) % 3; nch = 3; }
  const int len = i2 + 1;
  const int k0 = (c * len) / nch, k1 = ((c + 1) * len) / nch;
  const int kvh = blockIdx.y, b = blockIdx.z;
  const int t = threadIdx.x, w = t >> 6, lane = t & 63;
  const int m16 = lane & 15, quad = lane >> 4;
  const int h = kvh * 4 + w;

  const bf16* Qp = qbuf + (((size_t)(b * NHEADS + h)) * S_LEN + i2 * 32 + m16) * HDIM;
  short8 qf[2][4];
#pragma unroll
  for (int T = 0; T < 2; ++T)
#pragma unroll
    for (int cc = 0; cc < 4; ++cc)
      qf[T][cc] = *reinterpret_cast<const short8*>(Qp + (size_t)T * 16 * HDIM + cc * 32 + quad * 8);

  const bf16* Kp  = kbuf  + ((size_t)(b * NKVH + kvh)) * S_LEN * HDIM;
  const bf16* Vtp = vtbuf + ((size_t)(b * NKVH + kvh)) * HDIM * S_LEN;

  const int kk = lane >> 4, cK = lane & 15;
  const int rKa = w * 8 + kk, rKb = rKa + 4;
  const int offKa = rKa * 128 + ((cK ^ (rKa & 7)) * 8);
  const int offKb = rKb * 128 + ((cK ^ (rKb & 7)) * 8);
  const int dd = lane >> 2, cV = lane & 3;
  const int dVa = w * 32 + dd, dVb = dVa + 16;
  const int offVa = dVa * 2048 + ((cV ^ ((dVa >> 1) & 3)) * 8);
  const int offVb = dVb * 2048 + ((cV ^ ((dVb >> 1) & 3)) * 8);

  const floatx4 zf = {0.f, 0.f, 0.f, 0.f};
  floatx4 oacc[2][8];
#pragma unroll
  for (int T = 0; T < 2; ++T)
#pragma unroll
    for (int d = 0; d < 8; ++d) oacc[T][d] = zf;
  floatx4 lacc[2] = {zf, zf};
  unsigned short ones_s[8] = {0x3F80,0x3F80,0x3F80,0x3F80,0x3F80,0x3F80,0x3F80,0x3F80};
  const short8 ones = *reinterpret_cast<short8*>(ones_s);

  unsigned short* Pw = &Ps[w][0];

  {
    const int ks = k0 * 32;
    async_copy16(Kp + (size_t)ks * 128 + offKa, &Ks[0][w * 1024]);
    async_copy16(Kp + (size_t)ks * 128 + offKb, &Ks[0][w * 1024 + 512]);
    async_copy16(Vtp + ks + offVa, &Vs[0][w * 1024]);
    async_copy16(Vtp + ks + offVb, &Vs[0][w * 1024 + 512]);
  }
  __syncthreads();

  for (int ki = k0; ki < k1; ++ki) {
    const int buf = (ki - k0) & 1;
    if (ki + 1 < k1) {
      const int ks = (ki + 1) * 32;
      async_copy16(Kp + (size_t)ks * 128 + offKa, &Ks[buf ^ 1][w * 1024]);
      async_copy16(Kp + (size_t)ks * 128 + offKb, &Ks[buf ^ 1][w * 1024 + 512]);
      async_copy16(Vtp + ks + offVa, &Vs[buf ^ 1][w * 1024]);
      async_copy16(Vtp + ks + offVb, &Vs[buf ^ 1][w * 1024 + 512]);
    }
    const int ks = ki * 32;
    floatx4 s00 = zf, s01 = zf, s10 = zf, s11 = zf;
#pragma unroll
    for (int cc = 0; cc < 4; ++cc) {
      const int sw = ((cc * 4 + quad) ^ (m16 & 7)) * 8;
      short8 kf0 = *reinterpret_cast<const short8*>(&Ks[buf][m16 * 128 + sw]);
      short8 kf1 = *reinterpret_cast<const short8*>(&Ks[buf][(16 + m16) * 128 + sw]);
      s00 = __builtin_amdgcn_mfma_f32_16x16x32_bf16(qf[0][cc], kf0, s00, 0, 0, 0);
      s01 = __builtin_amdgcn_mfma_f32_16x16x32_bf16(qf[0][cc], kf1, s01, 0, 0, 0);
      s10 = __builtin_amdgcn_mfma_f32_16x16x32_bf16(qf[1][cc], kf0, s10, 0, 0, 0);
      s11 = __builtin_amdgcn_mfma_f32_16x16x32_bf16(qf[1][cc], kf1, s11, 0, 0, 0);
    }
#pragma unroll
    for (int T = 0; T < 2; ++T) {
      const floatx4& sa = T ? s10 : s00;
      const floatx4& sb = T ? s11 : s01;
#pragma unroll
      for (int r = 0; r < 4; ++r) {
        const int row = i2 * 32 + T * 16 + quad * 4 + r;
        const float p0 = (ks + m16      > row) ? 0.f : __expf(sa[r]);
        const float p1 = (ks + 16 + m16 > row) ? 0.f : __expf(sb[r]);
        Pw[(T * 16 + quad * 4 + r) * 40 + m16]      = cvt1(p0);
        Pw[(T * 16 + quad * 4 + r) * 40 + 16 + m16] = cvt1(p1);
      }
    }
    const short8 pa0 = *reinterpret_cast<const short8*>(&Pw[m16 * 40 + quad * 8]);
    const short8 pa1 = *reinterpret_cast<const short8*>(&Pw[(16 + m16) * 40 + quad * 8]);
    lacc[0] = __builtin_amdgcn_mfma_f32_16x16x32_bf16(pa0, ones, lacc[0], 0, 0, 0);
    lacc[1] = __builtin_amdgcn_mfma_f32_16x16x32_bf16(pa1, ones, lacc[1], 0, 0, 0);
#pragma unroll
    for (int dt = 0; dt < 8; ++dt) {
      short8 vfr = *reinterpret_cast<const short8*>(
          &Vs[buf][(dt * 16 + m16) * 32 + ((quad ^ ((m16 >> 1) & 3)) * 8)]);
      oacc[0][dt] = __builtin_amdgcn_mfma_f32_16x16x32_bf16(pa0, vfr, oacc[0][dt], 0, 0, 0);
      oacc[1][dt] = __builtin_amdgcn_mfma_f32_16x16x32_bf16(pa1, vfr, oacc[1][dt], 0, 0, 0);
    }
    __syncthreads();
  }

  if (nch == 1) {
    // final: divide by row-sum, write abuf directly
#pragma unroll
    for (int T = 0; T < 2; ++T) {
      float invl[4];
#pragma unroll
      for (int r = 0; r < 4; ++r) invl[r] = 1.0f / lacc[T][r];
      bf16* op = abuf + (((size_t)b * S_LEN + i2 * 32 + T * 16 + quad * 4) * NHEADS + h) * HDIM + m16;
#pragma unroll
      for (int dt = 0; dt < 8; ++dt)
#pragma unroll
        for (int r = 0; r < 4; ++r)
          op[(size_t)r * NHEADS * HDIM + dt * 16] = __float2bfloat16(oacc[T][dt][r] * invl[r]);
    }
  } else {
    const int b0 = (i2 < 54) ? (27 + 2 * (i2 - 27)) : (81 + 3 * (i2 - 54));
    const int slot = (b * NHEADS + h) * 111 + b0 + c;
    unsigned short* np = pnum + (size_t)slot * 4096;
#pragma unroll
    for (int T = 0; T < 2; ++T)
#pragma unroll
      for (int dt = 0; dt < 8; ++dt)
#pragma unroll
        for (int r = 0; r < 4; ++r)
          np[(T * 16 + quad * 4 + r) * 128 + dt * 16 + m16] = cvt1(oacc[T][dt][r]);
    if (m16 == 0) {
#pragma unroll
      for (int T = 0; T < 2; ++T)
#pragma unroll
        for (int r = 0; r < 4; ++r)
          plsum[slot * 32 + T * 16 + quad * 4 + r] = lacc[T][r];
    }
  }
}

// ---------------- Attention phase B: combine multi-chunk tiles only ----------
__global__ __launch_bounds__(256) void attn_combine(const unsigned short* __restrict__ pnum,
                                                    const float* __restrict__ plsum,
                                                    bf16* __restrict__ abuf)
{
  const int i = 54 + blockIdx.x;                     // 16-row tiles 54..127
  const int h = blockIdx.y, b = blockIdx.z;
  const int i2 = i >> 1, lr0 = (i & 1) * 16;
  const int t = threadIdx.x, row16 = t >> 4, c0 = (t & 15) * 8;
  const int lr = lr0 + row16;
  const int nch = (i2 < 54) ? 2 : 3;
  const int b0  = (i2 < 54) ? (27 + 2 * (i2 - 27)) : (81 + 3 * (i2 - 54));
  const int hb = (b * NHEADS + h) * 111 + b0;
  float acc[8] = {0.f,0.f,0.f,0.f,0.f,0.f,0.f,0.f};
  float lsum = 0.f;
  for (int c = 0; c < nch; ++c) {
    const unsigned short* np = pnum + (size_t)(hb + c) * 4096 + lr * 128 + c0;
    const short8 v = *reinterpret_cast<const short8*>(np);
#pragma unroll
    for (int j = 0; j < 8; ++j) acc[j] += us2f(((unsigned short*)&v)[j]);
    lsum += plsum[(hb + c) * 32 + lr];
  }
  const float invl = 1.0f / lsum;
  unsigned short o[8];
#pragma unroll
  for (int j = 0; j < 8; ++j) o[j] = cvt1(acc[j] * invl);
  *reinterpret_cast<short8*>(abuf + (((size_t)b * S_LEN + i * 16 + row16) * NHEADS + h) * HDIM + c0)
      = *reinterpret_cast<short8*>(o);
}

extern "C" void kernel_launch(void* const* d_in, const int* in_sizes, int n_in,
                              void* d_out, int out_size, void* d_ws, size_t ws_size,
                              hipStream_t stream) {
  const float* hidden_f = (const float*)d_in[0];
  const float* wqkv_f   = (const float*)d_in[1];
  const float* wout_f   = (const float*)d_in[2];
  float* out = (float*)d_out;

  char* ws = (char*)d_ws;
  bf16* hbf    = (bf16*)(ws);                    // [4096,2048]   (dead after gemm0)
  bf16* wqkvbf = (bf16*)(ws + 16777216);         // [3072,2048]   (dead after gemm0)
  bf16* woutbf = (bf16*)(ws + 29360128);         // [2048,2048]
  bf16* qbuf   = (bf16*)(ws + 37748736);         // [B,NH,S,HD]
  bf16* kbuf   = (bf16*)(ws + 54525952);         // [B,NKV,S,HD]
  bf16* vtbuf  = (bf16*)(ws + 58720256);         // [B,NKV,HD,S]
  bf16* abuf   = (bf16*)(ws + 62914560);         // [B,S,NH,HD]
  unsigned short* pnum = (unsigned short*)(ws);  // overlay: 3552 x 8KB = 29.1 MB
  float* plsum = (float*)(ws + 79691776);        // 3552 x 32 fp32 (0.45 MB)

  cvt_all<<<9216, 256, 0, stream>>>(hidden_f, wqkv_f, wout_f, (unsigned short*)ws);

  gemm8<0><<<dim3(12, 16), 512, 0, stream>>>(hbf, wqkvbf, qbuf, kbuf, vtbuf, nullptr);
  attn_partial<<<dim3(111, 4, 2), 256, 0, stream>>>(qbuf, kbuf, vtbuf, pnum, plsum, abuf);
  attn_combine<<<dim3(74, 16, 2), 256, 0, stream>>>(pnum, plsum, abuf);
  gemm8<1><<<dim3(8, 32), 512, 0, stream>>>(abuf, woutbf, nullptr, nullptr, nullptr, out);
}